// Round 5
// baseline (23.224 us; speedup 1.0000x reference)
//
#include <hip/hip_runtime.h>

#define HH 128
#define WW 192
#define HW (HH * WW)

typedef float f32x2 __attribute__((ext_vector_type(2)));
typedef float f32x4 __attribute__((ext_vector_type(4)));

// Forced VOP3P packed fp32 FMA. d = a*b + c elementwise on 2 floats.
__device__ __forceinline__ f32x2 pkfma(f32x2 a, f32x2 b, f32x2 c) {
    f32x2 d;
    asm("v_pk_fma_f32 %0, %1, %2, %3" : "=v"(d) : "v"(a), "v"(b), "v"(c));
    return d;
}
// d = a * broadcast(b[0]) + c   (op_sel_hi[src1]=0 -> hi half reads b.lo)
__device__ __forceinline__ f32x2 pkfma_blo(f32x2 a, f32x2 b, f32x2 c) {
    f32x2 d;
    asm("v_pk_fma_f32 %0, %1, %2, %3 op_sel:[0,0,0] op_sel_hi:[1,0,1]"
        : "=v"(d) : "v"(a), "v"(b), "v"(c));
    return d;
}
// d = a * broadcast(b[1]) + c   (op_sel[src1]=1 -> lo half reads b.hi)
__device__ __forceinline__ f32x2 pkfma_bhi(f32x2 a, f32x2 b, f32x2 c) {
    f32x2 d;
    asm("v_pk_fma_f32 %0, %1, %2, %3 op_sel:[0,1,0] op_sel_hi:[1,1,1]"
        : "=v"(d) : "v"(a), "v"(b), "v"(c));
    return d;
}
__device__ __forceinline__ f32x2 vrelu2(f32x2 v) {
    return __builtin_elementwise_max(v, (f32x2){0.f, 0.f});
}
__device__ __forceinline__ float relu(float v) { return fmaxf(v, 0.0f); }

// LDS weight layout (176 floats; all pair-reads land on even indices):
// [0..7] w0x[o]  [8..15] w0y[o]  [16..23] b0[o]
// [24..87] w0t[ch][o]  [88..151] w1t[i][o]
// [152..159] w2[o]  [160..167] b1[o]  [168] b2

__global__ __launch_bounds__(512, 4) void dmh_kernel(
    const float* __restrict__ mask_feats,   // (4,8,128,192)
    const float* __restrict__ params,       // (128,169)
    const float* __restrict__ locs,         // (128,2)
    const float* __restrict__ soi,          // (5,)
    const int*   __restrict__ im_inds,      // (128,)
    const int*   __restrict__ fpn_levels,   // (128,)
    const int*   __restrict__ stride_p,     // scalar (=8)
    float*       __restrict__ out)          // (128,1,256,384)
{
    const int tid = threadIdx.x;
    const int c0 = blockIdx.x * 64;   // source col tile origin
    const int r0 = blockIdx.y * 32;   // source row tile origin
    const int n  = blockIdx.z;        // instance

    __shared__ float sW[176];
    __shared__ float tile[33 * 66];   // rows -1..31 -> 0..32, cols -1..63 -> 0..64

    // ---- stage + transpose weights into LDS ----
    if (tid < 169) {
        float v = params[(size_t)n * 169 + tid];
        int d;
        if (tid < 80)       { int o = tid / 10, r = tid - o * 10;
                              d = (r == 0) ? o : (r == 1) ? (8 + o) : (24 + (r - 2) * 8 + o); }
        else if (tid < 144) { int t = tid - 80, o = t >> 3, i = t & 7; d = 88 + i * 8 + o; }
        else if (tid < 152) d = 152 + (tid - 144);
        else if (tid < 160) d = 16 + (tid - 152);
        else if (tid < 168) d = 160 + (tid - 160);
        else                d = 168;
        sW[d] = v;
    }

    const int   stride = *stride_p;                 // 8
    const float half   = 0.5f * (float)stride;      // 4.0
    const float locx = locs[2 * n + 0];
    const float locy = locs[2 * n + 1];
    const float inv  = 1.0f / soi[fpn_levels[n]];
    const float* fb  = mask_feats + (size_t)im_inds[n] * 8 * HW;

    __syncthreads();

    const f32x2* __restrict__ sW2 = reinterpret_cast<const f32x2*>(sW);
    // pair-index map: w0x q: sW2[q], w0y: sW2[4+q], b0: sW2[8+q],
    // w0t[ch] q: sW2[12+ch*4+q], w1t[i] q: sW2[44+i*4+q],
    // w2: sW2[76+q], b1: sW2[80+q], b2: sW[168]

    // ---------- phase 1a: interior 32x64, 4 contiguous px per thread ----------
    {
        const int ir = tid >> 4;          // 0..31
        const int ic = (tid & 15) << 2;   // 0,4,...,60
        const int rr = r0 + ir, cc = c0 + ic;   // always in-bounds
        const float* fp = fb + rr * WW + cc;

        f32x4 xv[8];
        #pragma unroll
        for (int ch = 0; ch < 8; ++ch)
            xv[ch] = *reinterpret_cast<const f32x4*>(fp + ch * HW);

        const float rxd = -(float)stride * inv;
        float rx0 = (locx - (float)(cc * stride) - half) * inv;
        f32x2 rxA = {rx0, rx0 + rxd};
        f32x2 rxB = {rx0 + 2.f * rxd, rx0 + 3.f * rxd};
        const float ry = (locy - (float)(rr * stride) - half) * inv;
        f32x2 ryp = {ry, ry};

        // h[q][p]: output-channel pair {2q,2q+1} at pixel p
        f32x2 h[4][4];
        #pragma unroll
        for (int q = 0; q < 4; ++q) {
            f32x2 t = pkfma_blo(sW2[4 + q], ryp, sW2[8 + q]);   // w0y*ry + b0
            h[q][0] = pkfma_blo(sW2[q], rxA, t);
            h[q][1] = pkfma_bhi(sW2[q], rxA, t);
            h[q][2] = pkfma_blo(sW2[q], rxB, t);
            h[q][3] = pkfma_bhi(sW2[q], rxB, t);
        }
        #pragma unroll
        for (int ch = 0; ch < 8; ++ch) {
            f32x2 xlo = __builtin_shufflevector(xv[ch], xv[ch], 0, 1);
            f32x2 xhi = __builtin_shufflevector(xv[ch], xv[ch], 2, 3);
            #pragma unroll
            for (int q = 0; q < 4; ++q) {
                f32x2 w = sW2[12 + ch * 4 + q];
                h[q][0] = pkfma_blo(w, xlo, h[q][0]);
                h[q][1] = pkfma_bhi(w, xlo, h[q][1]);
                h[q][2] = pkfma_blo(w, xhi, h[q][2]);
                h[q][3] = pkfma_bhi(w, xhi, h[q][3]);
            }
        }
        // relu
        f32x2 v[4][4];
        #pragma unroll
        for (int q = 0; q < 4; ++q)
            #pragma unroll
            for (int p = 0; p < 4; ++p) v[q][p] = vrelu2(h[q][p]);

        // layer 1 (i=0 folds the b1 bias as the accumulator init)
        f32x2 a[4][4];
        #pragma unroll
        for (int q = 0; q < 4; ++q) {
            f32x2 w = sW2[44 + q];        // w1t[i=0]
            f32x2 b = sW2[80 + q];        // b1 pair
            a[q][0] = pkfma_blo(w, v[0][0], b);
            a[q][1] = pkfma_blo(w, v[0][1], b);
            a[q][2] = pkfma_blo(w, v[0][2], b);
            a[q][3] = pkfma_blo(w, v[0][3], b);
        }
        #pragma unroll
        for (int i = 1; i < 8; ++i) {
            const int q2 = i >> 1;
            #pragma unroll
            for (int q = 0; q < 4; ++q) {
                f32x2 w = sW2[44 + i * 4 + q];
                if (i & 1) {
                    a[q][0] = pkfma_bhi(w, v[q2][0], a[q][0]);
                    a[q][1] = pkfma_bhi(w, v[q2][1], a[q][1]);
                    a[q][2] = pkfma_bhi(w, v[q2][2], a[q][2]);
                    a[q][3] = pkfma_bhi(w, v[q2][3], a[q][3]);
                } else {
                    a[q][0] = pkfma_blo(w, v[q2][0], a[q][0]);
                    a[q][1] = pkfma_blo(w, v[q2][1], a[q][1]);
                    a[q][2] = pkfma_blo(w, v[q2][2], a[q][2]);
                    a[q][3] = pkfma_blo(w, v[q2][3], a[q][3]);
                }
            }
        }

        // layer 2: pair-wise dot, horizontal add at the end
        f32x2 zz = {0.f, 0.f};
        f32x2 lgp[4] = {zz, zz, zz, zz};
        #pragma unroll
        for (int q = 0; q < 4; ++q) {
            f32x2 w2q = sW2[76 + q];
            #pragma unroll
            for (int p = 0; p < 4; ++p)
                lgp[p] = pkfma(w2q, vrelu2(a[q][p]), lgp[p]);
        }
        const float b2v = sW[168];
        #pragma unroll
        for (int p = 0; p < 4; ++p)
            tile[(ir + 1) * 66 + ic + 1 + p] = lgp[p][0] + lgp[p][1] + b2v;
    }

    // ---------- phase 1b: 97 halo px (row -1, col -1), scalar ----------
    if (tid < 97) {
        int r, c;
        if (tid < 65) { r = -1; c = tid - 1; }      // row -1, cols -1..63
        else          { r = tid - 65; c = -1; }     // rows 0..31, col -1
        int hr = min(max(r0 + r, 0), HH - 1);
        int hc = min(max(c0 + c, 0), WW - 1);
        const float* hfp = fb + hr * WW + hc;
        float rx  = (locx - (float)(hc * stride) - half) * inv;
        float ry2 = (locy - (float)(hr * stride) - half) * inv;
        float hh[8];
        #pragma unroll
        for (int o = 0; o < 8; ++o)
            hh[o] = fmaf(sW[o], rx, fmaf(sW[8 + o], ry2, sW[16 + o]));
        #pragma unroll
        for (int ch = 0; ch < 8; ++ch) {
            float x = hfp[ch * HW];
            #pragma unroll
            for (int o = 0; o < 8; ++o) hh[o] = fmaf(sW[24 + ch * 8 + o], x, hh[o]);
        }
        float aa[8];
        #pragma unroll
        for (int o = 0; o < 8; ++o) aa[o] = sW[160 + o];
        #pragma unroll
        for (int i = 0; i < 8; ++i) {
            float v = relu(hh[i]);
            #pragma unroll
            for (int o = 0; o < 8; ++o) aa[o] = fmaf(sW[88 + i * 8 + o], v, aa[o]);
        }
        float lg = sW[168];
        #pragma unroll
        for (int o = 0; o < 8; ++o) lg = fmaf(sW[152 + o], relu(aa[o]), lg);
        tile[(r + 1) * 66 + (c + 1)] = lg;
    }
    __syncthreads();

    // ---------- phase 2: x2 aligned upsample -> 64x128 output tile ----------
    const int kx = tid & 31;          // 32 groups of 4 output cols
    const int ky = tid >> 5;          // 16 row groups of 4 rows
    float* ob = out + ((size_t)n * 256 + 2 * r0) * 384 + 2 * c0 + 4 * kx;
    #pragma unroll
    for (int yy = 0; yy < 4; ++yy) {
        int yt = ky * 4 + yy;         // 0..63
        int i  = 2 * r0 + yt - 1;
        int rb = i >> 1;              // arithmetic shift handles i=-1
        int fy = i & 1;
        float wy0 = fy ? 0.5f : 1.0f;
        float wy1 = fy ? 0.5f : 0.0f;
        int lr  = rb - r0 + 1;        // in [0,32]
        int lr2 = lr + fy;            // in [0,32]
        const float* ra = &tile[lr  * 66 + 2 * kx];
        const float* rc = &tile[lr2 * 66 + 2 * kx];
        float t0 = fmaf(wy1, rc[0], wy0 * ra[0]);
        float t1 = fmaf(wy1, rc[1], wy0 * ra[1]);
        float t2 = fmaf(wy1, rc[2], wy0 * ra[2]);
        float4 o4;
        o4.x = 0.5f * (t0 + t1);
        o4.y = t1;
        o4.z = 0.5f * (t1 + t2);
        o4.w = t2;
        *reinterpret_cast<float4*>(ob + (size_t)yt * 384) = o4;
    }
}

extern "C" void kernel_launch(void* const* d_in, const int* in_sizes, int n_in,
                              void* d_out, int out_size, void* d_ws, size_t ws_size,
                              hipStream_t stream) {
    const float* mask_feats = (const float*)d_in[0];
    const float* params     = (const float*)d_in[1];
    const float* locs       = (const float*)d_in[2];
    const float* soi        = (const float*)d_in[3];
    const int*   im_inds    = (const int*)d_in[4];
    const int*   fpn_levels = (const int*)d_in[5];
    const int*   stride_p   = (const int*)d_in[6];
    float* out = (float*)d_out;

    dim3 grid(WW / 64, HH / 32, 128);   // (3, 4, 128)
    dim3 block(512);
    dmh_kernel<<<grid, block, 0, stream>>>(
        mask_feats, params, locs, soi, im_inds, fpn_levels, stride_p, out);
}